// Round 11
// baseline (180.369 us; speedup 1.0000x reference)
//
#include <hip/hip_runtime.h>

#define F_IN 256
#define F_OUT 64
#define BSH 7             // bin width 128 nodes
#define BINW 128
#define NBINS_CAP 512     // LDS histogram capacity in bin_count (N <= 65536)
#define BATCH 4096        // edges per bin block (16 per thread at 256 thr)
#define CSTRIDE 16        // cursor padded to one 64B line per bin (R9)
#define MAXBIN_CAP 2560   // per-bin staging capacity (mean 2047, ~11 sd)

typedef __attribute__((ext_vector_type(8))) short short8;
typedef __attribute__((ext_vector_type(4))) float f32x4;

// ---------------------------------------------------------------------------
// bf16 helpers. Hot-path pack via HW v_cvt_pk_bf16_f32 (RNE, 2 floats/instr).
// ---------------------------------------------------------------------------
__device__ inline float bf_lo(unsigned u) { return __uint_as_float(u << 16); }
__device__ inline float bf_hi(unsigned u) { return __uint_as_float(u & 0xFFFF0000u); }
__device__ inline unsigned cvt_pk_bf16(float lo, float hi) {
    unsigned r;
    asm("v_cvt_pk_bf16_f32 %0, %1, %2" : "=v"(r) : "v"(lo), "v"(hi));
    return r;
}
__device__ inline short8 pack_cvt(float4 a, float4 b) {
    union { unsigned u[4]; short8 s; } r;
    r.u[0] = cvt_pk_bf16(a.x, a.y);
    r.u[1] = cvt_pk_bf16(a.z, a.w);
    r.u[2] = cvt_pk_bf16(b.x, b.y);
    r.u[3] = cvt_pk_bf16(b.z, b.w);
    return r.s;
}

// ---------------------------------------------------------------------------
// K1: bin edges into per-bin staging (R4-proven cursor-atomic body; R10's
// deterministic variant measured SLOWER — slot scans cost more than the
// atomics they avoided) + feed global deg[dst] with no-return atomics (R9
// proven). deg decouples the gemm from the staging entirely (R20).
// R15: staging chunk writes contiguous per (block,bin). R16: LDS atomics
// index __shared__ arrays directly.
// ---------------------------------------------------------------------------
__global__ __launch_bounds__(256) void bin_deg(const int* __restrict__ adj,
                                               unsigned* __restrict__ staging,
                                               int* __restrict__ cursor,
                                               int* __restrict__ deg,
                                               int E, int nbins, int maxBin) {
    __shared__ int cnt[NBINS_CAP];
    __shared__ int base[NBINS_CAP];
    const int tid = threadIdx.x;
    for (int i = tid; i < NBINS_CAP; i += 256) cnt[i] = 0;
    __syncthreads();

    const int e0 = blockIdx.x * BATCH + tid * 16;
    int S[16], D[16], sl[16];
    int nv = 0;
    if (e0 + 16 <= E) {
#pragma unroll
        for (int k = 0; k < 4; k++) {
            *(int4*)&S[k * 4] = *(const int4*)&adj[e0 + k * 4];
            *(int4*)&D[k * 4] = *(const int4*)&adj[E + e0 + k * 4];
        }
        nv = 16;
    } else if (e0 < E) {
        for (int k = 0; k < 16 && e0 + k < E; k++) {
            S[k] = adj[e0 + k];
            D[k] = adj[E + e0 + k];
            nv++;
        }
    }
#pragma unroll
    for (int j = 0; j < 16; j++) {
        if (j < nv) {
            sl[j] = atomicAdd(&cnt[D[j] >> BSH], 1);
            atomicAdd(&deg[D[j]], 1);  // no-return global atomic (R5/R9 proven)
        }
    }
    __syncthreads();
    for (int i = tid; i < nbins; i += 256) {
        int cv = cnt[i];
        base[i] = cv ? atomicAdd(&cursor[i * CSTRIDE], cv) : 0;
    }
    __syncthreads();
#pragma unroll
    for (int j = 0; j < 16; j++) {
        if (j < nv) {
            int b = D[j] >> BSH;
            int pos = base[b] + sl[j];
            if (pos < maxBin)
                staging[(size_t)b * maxBin + pos] =
                    (unsigned)S[j] | ((unsigned)(D[j] & (BINW - 1)) << 16);
        }
    }
}

// ---------------------------------------------------------------------------
// K2: g(bf16) = dinv[n] * (x @ W) via bf16 MFMA (proven R13 body). R20:
// dinv from the deg array via ONE coalesced 256B load per block — no
// segment scan, no LDS histogram (that scan was why every gemm variant sat
// at ~40-50us). 64 nodes/block, 782 blocks x 256 thr (4 waves): 3.05
// blocks/CU vs 1.53 — R8's half-bin penalty was the duplicated segment
// scan, which no longer exists; W-load duplication is 25MB of L2 reads.
// ---------------------------------------------------------------------------
__global__ __launch_bounds__(256, 4) void gemm_mfma(const float* __restrict__ x,
                                                    const float* __restrict__ W,
                                                    const int* __restrict__ deg,
                                                    unsigned* __restrict__ gu, int N) {
    __shared__ unsigned Wf[32 * 64 * 4];  // 32 KB: [kchunk][n][4 x u32(bf16x2)]
    __shared__ float dinvL[64];
    const int b = blockIdx.x;
    const int tid = threadIdx.x;
    const int nb0 = b * 64;

    if (tid < 64) {
        int gn = min(nb0 + tid, N - 1);
        dinvL[tid] = rsqrtf((float)deg[gn] + 1.0f);
    }
    for (int p = tid; p < (F_IN / 2) * F_OUT; p += 256) {
        int kp = p >> 6;
        int n = p & 63;
        int k = kp * 2;
        Wf[((k >> 3) * 64 + n) * 4 + ((k & 7) >> 1)] =
            cvt_pk_bf16(W[k * F_OUT + n], W[(k + 1) * F_OUT + n]);
    }
    __syncthreads();

    const int wave = tid >> 6;   // 0..3
    const int lane = tid & 63;
    const int q = lane >> 4;
    const int c = lane & 15;
    const int n0 = nb0 + wave * 16;
    const int r = min(n0 + c, N - 1);
    const float* p0 = x + (size_t)r * F_IN + q * 8;

    f32x4 acc[4] = {};
#pragma unroll
    for (int s = 0; s < 8; s++) {
        float4 a0 = *(const float4*)(p0 + s * 32);
        float4 a1 = *(const float4*)(p0 + s * 32 + 4);
        short8 ah = pack_cvt(a0, a1);
#pragma unroll
        for (int t = 0; t < 4; t++) {
            short8 bh = *(const short8*)&Wf[((s * 4 + q) * 64 + t * 16 + c) * 4];
            acc[t] = __builtin_amdgcn_mfma_f32_16x16x32_bf16(ah, bh, acc[t], 0, 0, 0);
        }
    }

    // D layout: col = t*16 + c (feature), row = q*4 + rr (node). Pack col
    // pairs via shfl_xor(1), store bf16x2.
#pragma unroll
    for (int rr = 0; rr < 4; rr++) {
        int node = n0 + q * 4 + rr;
        float dv = dinvL[wave * 16 + q * 4 + rr];
#pragma unroll
        for (int t = 0; t < 4; t++) {
            float v = acc[t][rr] * dv;
            float o = __shfl_xor(v, 1, 64);
            if (node < N && !(lane & 1)) {
                gu[(size_t)node * 32 + t * 8 + (c >> 1)] = cvt_pk_bf16(v, o);
            }
        }
    }
}

// ---------------------------------------------------------------------------
// K3: gather via bin-local CSR in LDS (R7 proven body, verbatim). One block
// per 128-node bin: histogram + 2-wave scan + scatter staged segment into
// binCsr[2560] u16 (all LDS-direct), then register-accumulate gather:
// wave = 16 nodes, 8 groups x 8 lanes, one coalesced 128B g-row per edge,
// 2-deep unroll, shfl_xor cross-group reduce, fused self+dinv+bias+relu.
// ---------------------------------------------------------------------------
__global__ __launch_bounds__(512) void gather_bin(const unsigned* __restrict__ staging,
                                                  const int* __restrict__ cursor,
                                                  const unsigned* __restrict__ g32,
                                                  const float* __restrict__ bias,
                                                  float* __restrict__ out,
                                                  int N, int maxBin) {
    __shared__ int cnt[BINW];
    __shared__ int off[BINW];
    __shared__ int wsum[2];
    __shared__ unsigned short binCsr[MAXBIN_CAP];
    const int b = blockIdx.x;
    const int tid = threadIdx.x;
    const int nb0 = b << BSH;

    if (tid < BINW) cnt[tid] = 0;
    __syncthreads();

    const int segCnt = min(cursor[b * CSTRIDE], maxBin);
    const unsigned* seg = staging + (size_t)b * maxBin;

    unsigned ev[5];
    int sl[5];
    int nv = 0;
#pragma unroll
    for (int r = 0; r < 5; r++) {
        int i = tid + r * 512;
        if (i < segCnt) {
            unsigned e = seg[i];
            ev[r] = e;
            sl[r] = atomicAdd(&cnt[e >> 16], 1);
            nv = r + 1;
        }
    }
    __syncthreads();

    int incl = 0, v = 0;
    if (tid < BINW) {  // 2-wave exclusive scan of cnt[128]
        v = cnt[tid];
        incl = v;
        const int lane = tid & 63;
        for (int d = 1; d < 64; d <<= 1) {
            int t = __shfl_up(incl, d, 64);
            if (lane >= d) incl += t;
        }
        if (lane == 63) wsum[tid >> 6] = incl;
    }
    __syncthreads();
    if (tid < BINW) off[tid] = incl - v + ((tid >= 64) ? wsum[0] : 0);
    __syncthreads();

#pragma unroll
    for (int r = 0; r < 5; r++) {
        if (r < nv) binCsr[off[ev[r] >> 16] + sl[r]] = (unsigned short)(ev[r] & 0xFFFFu);
    }
    __syncthreads();

    const int wv = tid >> 6;
    const int lane = tid & 63;
    const int grp = lane >> 3;
    const int h = lane & 7;
    const uint4* g4 = (const uint4*)g32;

    for (int t = 0; t < 16; t++) {
        const int node = wv * 16 + t;
        const int gn = nb0 + node;
        if (gn >= N) break;
        const int start = off[node];
        const int deg = cnt[node];

        float a0[8] = {}, a1[8] = {};
        int i = grp;
        for (; i + 8 < deg; i += 16) {
            int s0 = binCsr[start + i], s1 = binCsr[start + i + 8];
            uint4 u0 = g4[(size_t)s0 * 8 + h];
            uint4 u1 = g4[(size_t)s1 * 8 + h];
            a0[0] += bf_lo(u0.x); a0[1] += bf_hi(u0.x);
            a0[2] += bf_lo(u0.y); a0[3] += bf_hi(u0.y);
            a0[4] += bf_lo(u0.z); a0[5] += bf_hi(u0.z);
            a0[6] += bf_lo(u0.w); a0[7] += bf_hi(u0.w);
            a1[0] += bf_lo(u1.x); a1[1] += bf_hi(u1.x);
            a1[2] += bf_lo(u1.y); a1[3] += bf_hi(u1.y);
            a1[4] += bf_lo(u1.z); a1[5] += bf_hi(u1.z);
            a1[6] += bf_lo(u1.w); a1[7] += bf_hi(u1.w);
        }
        if (i < deg) {
            int s0 = binCsr[start + i];
            uint4 u0 = g4[(size_t)s0 * 8 + h];
            a0[0] += bf_lo(u0.x); a0[1] += bf_hi(u0.x);
            a0[2] += bf_lo(u0.y); a0[3] += bf_hi(u0.y);
            a0[4] += bf_lo(u0.z); a0[5] += bf_hi(u0.z);
            a0[6] += bf_lo(u0.w); a0[7] += bf_hi(u0.w);
        }
        float acc[8];
#pragma unroll
        for (int k = 0; k < 8; k++) acc[k] = a0[k] + a1[k];
#pragma unroll
        for (int m = 8; m < 64; m <<= 1) {
#pragma unroll
            for (int k = 0; k < 8; k++) acc[k] += __shfl_xor(acc[k], m, 64);
        }
        if (grp == 0) {
            uint4 us = g4[(size_t)gn * 8 + h];  // self loop (dinv-prescaled)
            float dv = rsqrtf((float)deg + 1.0f);
            float s0 = bf_lo(us.x), s1 = bf_hi(us.x), s2 = bf_lo(us.y), s3 = bf_hi(us.y);
            float s4 = bf_lo(us.z), s5 = bf_hi(us.z), s6 = bf_lo(us.w), s7 = bf_hi(us.w);
            float4 b0 = *(const float4*)&bias[h * 8];
            float4 b1 = *(const float4*)&bias[h * 8 + 4];
            float4 r0, r1;
            r0.x = fmaxf(fmaf(dv, acc[0] + s0, b0.x), 0.0f);
            r0.y = fmaxf(fmaf(dv, acc[1] + s1, b0.y), 0.0f);
            r0.z = fmaxf(fmaf(dv, acc[2] + s2, b0.z), 0.0f);
            r0.w = fmaxf(fmaf(dv, acc[3] + s3, b0.w), 0.0f);
            r1.x = fmaxf(fmaf(dv, acc[4] + s4, b1.x), 0.0f);
            r1.y = fmaxf(fmaf(dv, acc[5] + s5, b1.y), 0.0f);
            r1.z = fmaxf(fmaf(dv, acc[6] + s6, b1.z), 0.0f);
            r1.w = fmaxf(fmaf(dv, acc[7] + s7, b1.w), 0.0f);
            *(float4*)&out[(size_t)gn * F_OUT + h * 8] = r0;
            *(float4*)&out[(size_t)gn * F_OUT + h * 8 + 4] = r1;
        }
    }
}

extern "C" void kernel_launch(void* const* d_in, const int* in_sizes, int n_in,
                              void* d_out, int out_size, void* d_ws, size_t ws_size,
                              hipStream_t stream) {
    const float* x = (const float*)d_in[0];
    const int* adj = (const int*)d_in[1];
    const float* W = (const float*)d_in[2];
    const float* b = (const float*)d_in[3];
    float* out = (float*)d_out;

    const int N = in_sizes[0] / F_IN;  // 50000 (u16 packing assumes N <= 65536)
    const int E = in_sizes[1] / 2;     // 800000
    const int nbins = (N + BINW - 1) >> BSH;   // 391 (<= NBINS_CAP)
    const int maxBin = MAXBIN_CAP;             // 2560
    const int nhalf = (N + 63) / 64;           // 782 gemm blocks

    // ws: [cursor(nbins*64B) | deg(N*4)] zeroed together | staging | g16
    char* ws = (char*)d_ws;
    size_t segCur = (((size_t)nbins * CSTRIDE * 4) + 255) & ~(size_t)255;
    size_t segDeg = (((size_t)N * 4) + 255) & ~(size_t)255;
    size_t segStg = (((size_t)nbins * maxBin * 4) + 255) & ~(size_t)255;
    int* cursor = (int*)ws;
    int* deg = (int*)(ws + segCur);
    unsigned* staging = (unsigned*)(ws + segCur + segDeg);
    unsigned* g16 = (unsigned*)(ws + segCur + segDeg + segStg);

    hipMemsetAsync(cursor, 0, segCur + segDeg, stream);  // cursors + deg

    bin_deg<<<(E + BATCH - 1) / BATCH, 256, 0, stream>>>(adj, staging, cursor,
                                                         deg, E, nbins, maxBin);
    gemm_mfma<<<nhalf, 256, 0, stream>>>(x, W, deg, g16, N);
    gather_bin<<<nbins, 512, 0, stream>>>(staging, cursor, g16, b, out, N, maxBin);
}

// Round 12
// 143.119 us; speedup vs baseline: 1.2603x; 1.2603x over previous
//
#include <hip/hip_runtime.h>

#define F_IN 256
#define F_OUT 64
#define BSH 7             // bin width 128 nodes
#define BINW 128
#define NBINS_CAP 512     // LDS histogram capacity in bin_count (N <= 65536)
#define BATCH 4096        // edges per block in bin_count (16 per thread, R13)
#define CSTRIDE 16        // cursor padded to one 64B line per bin (R9)
#define MAXBIN_CAP 2560   // per-bin staging capacity (mean 2047, ~11 sd)

typedef __attribute__((ext_vector_type(8))) short short8;
typedef __attribute__((ext_vector_type(4))) float f32x4;

// ---------------------------------------------------------------------------
// bf16 helpers. Hot-path pack via HW v_cvt_pk_bf16_f32 (RNE, 2 floats/instr).
// ---------------------------------------------------------------------------
__device__ inline float bf_lo(unsigned u) { return __uint_as_float(u << 16); }
__device__ inline float bf_hi(unsigned u) { return __uint_as_float(u & 0xFFFF0000u); }
__device__ inline unsigned cvt_pk_bf16(float lo, float hi) {
    unsigned r;
    asm("v_cvt_pk_bf16_f32 %0, %1, %2" : "=v"(r) : "v"(lo), "v"(hi));
    return r;
}
__device__ inline short8 pack_cvt(float4 a, float4 b) {
    union { unsigned u[4]; short8 s; } r;
    r.u[0] = cvt_pk_bf16(a.x, a.y);
    r.u[1] = cvt_pk_bf16(a.z, a.w);
    r.u[2] = cvt_pk_bf16(b.x, b.y);
    r.u[3] = cvt_pk_bf16(b.z, b.w);
    return r.s;
}

// ---------------------------------------------------------------------------
// K1: bin edges by dst>>BSH into per-bin staging (packed u32: src|dstLow<<16,
// N <= 65536). R7-proven verbatim. R21 rule: NO per-edge global atomics
// anywhere — 800k of them generate 30-40MB of coherence-point writeback
// (measured R5/R9/R11) and lose ~25-30us vs segment-scan deg. Cursor
// reservation here is only 77k atomics on padded lines.
// ---------------------------------------------------------------------------
__global__ __launch_bounds__(256) void bin_count(const int* __restrict__ adj,
                                                 unsigned* __restrict__ staging,
                                                 int* __restrict__ cursor,
                                                 int E, int nbins, int maxBin) {
    __shared__ int cnt[NBINS_CAP];
    __shared__ int base[NBINS_CAP];
    const int tid = threadIdx.x;
    for (int i = tid; i < NBINS_CAP; i += 256) cnt[i] = 0;
    __syncthreads();

    const int e0 = blockIdx.x * BATCH + tid * 16;
    int S[16], D[16], sl[16];
    int nv = 0;
    if (e0 + 16 <= E) {
#pragma unroll
        for (int k = 0; k < 4; k++) {
            *(int4*)&S[k * 4] = *(const int4*)&adj[e0 + k * 4];
            *(int4*)&D[k * 4] = *(const int4*)&adj[E + e0 + k * 4];
        }
        nv = 16;
    } else if (e0 < E) {
        for (int k = 0; k < 16 && e0 + k < E; k++) {
            S[k] = adj[e0 + k];
            D[k] = adj[E + e0 + k];
            nv++;
        }
    }
#pragma unroll
    for (int j = 0; j < 16; j++) {
        if (j < nv) sl[j] = atomicAdd(&cnt[D[j] >> BSH], 1);
    }
    __syncthreads();
    for (int i = tid; i < nbins; i += 256) {
        int cv = cnt[i];
        base[i] = cv ? atomicAdd(&cursor[i * CSTRIDE], cv) : 0;
    }
    __syncthreads();
#pragma unroll
    for (int j = 0; j < 16; j++) {
        if (j < nv) {
            int b = D[j] >> BSH;
            int pos = base[b] + sl[j];
            if (pos < maxBin)
                staging[(size_t)b * maxBin + pos] =
                    (unsigned)S[j] | ((unsigned)(D[j] & (BINW - 1)) << 16);
        }
    }
}

// ---------------------------------------------------------------------------
// K2: fused [bin deg-hist -> dinv] + [g(bf16) = dinv*(x @ W) via MFMA].
// R7-proven verbatim: deg from segment scan (no global atomics — R21),
// 391 blocks x 512 thr, W B-fragment-major LDS, cvt_pk pack.
// ---------------------------------------------------------------------------
__global__ __launch_bounds__(512, 4) void gemm_mfma(const float* __restrict__ x,
                                                    const float* __restrict__ W,
                                                    const unsigned* __restrict__ staging,
                                                    const int* __restrict__ cursor,
                                                    unsigned* __restrict__ gu,
                                                    int N, int maxBin) {
    __shared__ unsigned Wf[32 * 64 * 4];  // 32 KB: [kchunk][n][4 x u32(bf16x2)]
    __shared__ int degL[BINW];
    __shared__ float dinvL[BINW];
    const int b = blockIdx.x;
    const int tid = threadIdx.x;

    if (tid < BINW) degL[tid] = 0;
    for (int p = tid; p < (F_IN / 2) * F_OUT; p += 512) {
        int kp = p >> 6;
        int n = p & 63;
        int k = kp * 2;
        Wf[((k >> 3) * 64 + n) * 4 + ((k & 7) >> 1)] =
            cvt_pk_bf16(W[k * F_OUT + n], W[(k + 1) * F_OUT + n]);
    }
    __syncthreads();

    const int segCnt = min(cursor[b * CSTRIDE], maxBin);
    const unsigned* seg = staging + (size_t)b * maxBin;
    for (int i = tid; i < segCnt; i += 512) atomicAdd(&degL[seg[i] >> 16], 1);
    __syncthreads();
    if (tid < BINW) dinvL[tid] = rsqrtf((float)degL[tid] + 1.0f);
    __syncthreads();

    const int wave = tid >> 6;
    const int lane = tid & 63;
    const int q = lane >> 4;
    const int c = lane & 15;
    const int n0 = b * 128 + wave * 16;
    const int r = min(n0 + c, N - 1);
    const float* p0 = x + (size_t)r * F_IN + q * 8;

    f32x4 acc[4] = {};
#pragma unroll
    for (int s = 0; s < 8; s++) {
        float4 a0 = *(const float4*)(p0 + s * 32);
        float4 a1 = *(const float4*)(p0 + s * 32 + 4);
        short8 ah = pack_cvt(a0, a1);
#pragma unroll
        for (int t = 0; t < 4; t++) {
            short8 bh = *(const short8*)&Wf[((s * 4 + q) * 64 + t * 16 + c) * 4];
            acc[t] = __builtin_amdgcn_mfma_f32_16x16x32_bf16(ah, bh, acc[t], 0, 0, 0);
        }
    }

    // D layout: col = t*16 + c (feature), row = q*4 + rr (node). Pack col
    // pairs via shfl_xor(1), store bf16x2.
#pragma unroll
    for (int rr = 0; rr < 4; rr++) {
        int node = n0 + q * 4 + rr;
        float dv = dinvL[wave * 16 + q * 4 + rr];
#pragma unroll
        for (int t = 0; t < 4; t++) {
            float v = acc[t][rr] * dv;
            float o = __shfl_xor(v, 1, 64);
            if (node < N && !(lane & 1)) {
                gu[(size_t)node * 32 + t * 8 + (c >> 1)] = cvt_pk_bf16(v, o);
            }
        }
    }
}

// ---------------------------------------------------------------------------
// K3: gather via bin-local CSR in LDS. R22 change (single variable vs R7):
// 1024 threads/block -> 16 waves, 8 nodes/wave instead of 8 waves x 16
// nodes — halves the serial per-wave dependent-chain depth and doubles
// waves/CU (R10 measured: 27% occupancy, VALU 33%, 45us — latency-bound).
// CSR-build prologue re-strided for 1024 (3 rounds cover MAXBIN_CAP).
// Everything else verbatim R7.
// ---------------------------------------------------------------------------
__global__ __launch_bounds__(1024) void gather_bin(const unsigned* __restrict__ staging,
                                                   const int* __restrict__ cursor,
                                                   const unsigned* __restrict__ g32,
                                                   const float* __restrict__ bias,
                                                   float* __restrict__ out,
                                                   int N, int maxBin) {
    __shared__ int cnt[BINW];
    __shared__ int off[BINW];
    __shared__ int wsum[2];
    __shared__ unsigned short binCsr[MAXBIN_CAP];
    const int b = blockIdx.x;
    const int tid = threadIdx.x;
    const int nb0 = b << BSH;

    if (tid < BINW) cnt[tid] = 0;
    __syncthreads();

    const int segCnt = min(cursor[b * CSTRIDE], maxBin);
    const unsigned* seg = staging + (size_t)b * maxBin;

    unsigned ev[3];
    int sl[3];
    int nv = 0;
#pragma unroll
    for (int r = 0; r < 3; r++) {
        int i = tid + r * 1024;
        if (i < segCnt) {
            unsigned e = seg[i];
            ev[r] = e;
            sl[r] = atomicAdd(&cnt[e >> 16], 1);
            nv = r + 1;
        }
    }
    __syncthreads();

    int incl = 0, v = 0;
    if (tid < BINW) {  // 2-wave exclusive scan of cnt[128]
        v = cnt[tid];
        incl = v;
        const int lane = tid & 63;
        for (int d = 1; d < 64; d <<= 1) {
            int t = __shfl_up(incl, d, 64);
            if (lane >= d) incl += t;
        }
        if (lane == 63) wsum[tid >> 6] = incl;
    }
    __syncthreads();
    if (tid < BINW) off[tid] = incl - v + ((tid >= 64) ? wsum[0] : 0);
    __syncthreads();

#pragma unroll
    for (int r = 0; r < 3; r++) {
        if (r < nv) binCsr[off[ev[r] >> 16] + sl[r]] = (unsigned short)(ev[r] & 0xFFFFu);
    }
    __syncthreads();

    const int wv = tid >> 6;     // 0..15
    const int lane = tid & 63;
    const int grp = lane >> 3;
    const int h = lane & 7;
    const uint4* g4 = (const uint4*)g32;

    for (int t = 0; t < 8; t++) {  // 8 nodes per wave (was 16)
        const int node = wv * 8 + t;
        const int gn = nb0 + node;
        if (gn >= N) break;
        const int start = off[node];
        const int deg = cnt[node];

        float a0[8] = {}, a1[8] = {};
        int i = grp;
        for (; i + 8 < deg; i += 16) {
            int s0 = binCsr[start + i], s1 = binCsr[start + i + 8];
            uint4 u0 = g4[(size_t)s0 * 8 + h];
            uint4 u1 = g4[(size_t)s1 * 8 + h];
            a0[0] += bf_lo(u0.x); a0[1] += bf_hi(u0.x);
            a0[2] += bf_lo(u0.y); a0[3] += bf_hi(u0.y);
            a0[4] += bf_lo(u0.z); a0[5] += bf_hi(u0.z);
            a0[6] += bf_lo(u0.w); a0[7] += bf_hi(u0.w);
            a1[0] += bf_lo(u1.x); a1[1] += bf_hi(u1.x);
            a1[2] += bf_lo(u1.y); a1[3] += bf_hi(u1.y);
            a1[4] += bf_lo(u1.z); a1[5] += bf_hi(u1.z);
            a1[6] += bf_lo(u1.w); a1[7] += bf_hi(u1.w);
        }
        if (i < deg) {
            int s0 = binCsr[start + i];
            uint4 u0 = g4[(size_t)s0 * 8 + h];
            a0[0] += bf_lo(u0.x); a0[1] += bf_hi(u0.x);
            a0[2] += bf_lo(u0.y); a0[3] += bf_hi(u0.y);
            a0[4] += bf_lo(u0.z); a0[5] += bf_hi(u0.z);
            a0[6] += bf_lo(u0.w); a0[7] += bf_hi(u0.w);
        }
        float acc[8];
#pragma unroll
        for (int k = 0; k < 8; k++) acc[k] = a0[k] + a1[k];
#pragma unroll
        for (int m = 8; m < 64; m <<= 1) {
#pragma unroll
            for (int k = 0; k < 8; k++) acc[k] += __shfl_xor(acc[k], m, 64);
        }
        if (grp == 0) {
            uint4 us = g4[(size_t)gn * 8 + h];  // self loop (dinv-prescaled)
            float dv = rsqrtf((float)deg + 1.0f);
            float s0 = bf_lo(us.x), s1 = bf_hi(us.x), s2 = bf_lo(us.y), s3 = bf_hi(us.y);
            float s4 = bf_lo(us.z), s5 = bf_hi(us.z), s6 = bf_lo(us.w), s7 = bf_hi(us.w);
            float4 b0 = *(const float4*)&bias[h * 8];
            float4 b1 = *(const float4*)&bias[h * 8 + 4];
            float4 r0, r1;
            r0.x = fmaxf(fmaf(dv, acc[0] + s0, b0.x), 0.0f);
            r0.y = fmaxf(fmaf(dv, acc[1] + s1, b0.y), 0.0f);
            r0.z = fmaxf(fmaf(dv, acc[2] + s2, b0.z), 0.0f);
            r0.w = fmaxf(fmaf(dv, acc[3] + s3, b0.w), 0.0f);
            r1.x = fmaxf(fmaf(dv, acc[4] + s4, b1.x), 0.0f);
            r1.y = fmaxf(fmaf(dv, acc[5] + s5, b1.y), 0.0f);
            r1.z = fmaxf(fmaf(dv, acc[6] + s6, b1.z), 0.0f);
            r1.w = fmaxf(fmaf(dv, acc[7] + s7, b1.w), 0.0f);
            *(float4*)&out[(size_t)gn * F_OUT + h * 8] = r0;
            *(float4*)&out[(size_t)gn * F_OUT + h * 8 + 4] = r1;
        }
    }
}

extern "C" void kernel_launch(void* const* d_in, const int* in_sizes, int n_in,
                              void* d_out, int out_size, void* d_ws, size_t ws_size,
                              hipStream_t stream) {
    const float* x = (const float*)d_in[0];
    const int* adj = (const int*)d_in[1];
    const float* W = (const float*)d_in[2];
    const float* b = (const float*)d_in[3];
    float* out = (float*)d_out;

    const int N = in_sizes[0] / F_IN;  // 50000 (u16 packing assumes N <= 65536)
    const int E = in_sizes[1] / 2;     // 800000
    const int nbins = (N + BINW - 1) >> BSH;  // 391 (<= NBINS_CAP)
    const int maxBin = MAXBIN_CAP;            // 2560, ~11 sd above mean 2047

    // ws: cursor(nbins*64B, zeroed) | staging(nbins*maxBin u32) | g16(N*32 u32)
    char* ws = (char*)d_ws;
    size_t segCur = (((size_t)nbins * CSTRIDE * 4) + 255) & ~(size_t)255;
    size_t segStg = (((size_t)nbins * maxBin * 4) + 255) & ~(size_t)255;
    int* cursor = (int*)ws;
    unsigned* staging = (unsigned*)(ws + segCur);
    unsigned* g16 = (unsigned*)(ws + segCur + segStg);

    hipMemsetAsync(cursor, 0, segCur, stream);

    bin_count<<<(E + BATCH - 1) / BATCH, 256, 0, stream>>>(adj, staging, cursor,
                                                           E, nbins, maxBin);
    gemm_mfma<<<nbins, 512, 0, stream>>>(x, W, staging, cursor, g16, N, maxBin);
    gather_bin<<<nbins, 1024, 0, stream>>>(staging, cursor, g16, b, out, N, maxBin);
}

// Round 13
// 133.040 us; speedup vs baseline: 1.3558x; 1.0758x over previous
//
#include <hip/hip_runtime.h>

#define F_IN 256
#define F_OUT 64
#define BSH 7             // bin width 128 nodes
#define BINW 128
#define NBINS_CAP 512     // LDS histogram capacity in bin_count (N <= 65536)
#define BATCH 4096        // edges per block in bin_count (16 per thread, R13)
#define CSTRIDE 16        // cursor padded to one 64B line per bin (R9)
#define MAXBIN_CAP 2560   // per-bin staging capacity (mean 2047, ~11 sd)

typedef __attribute__((ext_vector_type(8))) short short8;
typedef __attribute__((ext_vector_type(4))) float f32x4;

// ---------------------------------------------------------------------------
// bf16 helpers. Hot-path pack via HW v_cvt_pk_bf16_f32 (RNE, 2 floats/instr).
// ---------------------------------------------------------------------------
__device__ inline float bf_lo(unsigned u) { return __uint_as_float(u << 16); }
__device__ inline float bf_hi(unsigned u) { return __uint_as_float(u & 0xFFFF0000u); }
__device__ inline unsigned cvt_pk_bf16(float lo, float hi) {
    unsigned r;
    asm("v_cvt_pk_bf16_f32 %0, %1, %2" : "=v"(r) : "v"(lo), "v"(hi));
    return r;
}
__device__ inline short8 pack_cvt(float4 a, float4 b) {
    union { unsigned u[4]; short8 s; } r;
    r.u[0] = cvt_pk_bf16(a.x, a.y);
    r.u[1] = cvt_pk_bf16(a.z, a.w);
    r.u[2] = cvt_pk_bf16(b.x, b.y);
    r.u[3] = cvt_pk_bf16(b.z, b.w);
    return r.s;
}

// ---------------------------------------------------------------------------
// K1: bin edges by dst>>BSH into per-bin staging (packed u32: src|dstLow<<16,
// N <= 65536). R7-proven verbatim. R21 rule: NO per-edge global atomics
// anywhere (800k of them = 30-40MB coherence writeback, measured R5/R9/R11).
// Cursor reservation is only 77k atomics on padded lines. R16 rule: LDS
// atomics index __shared__ arrays directly.
// ---------------------------------------------------------------------------
__global__ __launch_bounds__(256) void bin_count(const int* __restrict__ adj,
                                                 unsigned* __restrict__ staging,
                                                 int* __restrict__ cursor,
                                                 int E, int nbins, int maxBin) {
    __shared__ int cnt[NBINS_CAP];
    __shared__ int base[NBINS_CAP];
    const int tid = threadIdx.x;
    for (int i = tid; i < NBINS_CAP; i += 256) cnt[i] = 0;
    __syncthreads();

    const int e0 = blockIdx.x * BATCH + tid * 16;
    int S[16], D[16], sl[16];
    int nv = 0;
    if (e0 + 16 <= E) {
#pragma unroll
        for (int k = 0; k < 4; k++) {
            *(int4*)&S[k * 4] = *(const int4*)&adj[e0 + k * 4];
            *(int4*)&D[k * 4] = *(const int4*)&adj[E + e0 + k * 4];
        }
        nv = 16;
    } else if (e0 < E) {
        for (int k = 0; k < 16 && e0 + k < E; k++) {
            S[k] = adj[e0 + k];
            D[k] = adj[E + e0 + k];
            nv++;
        }
    }
#pragma unroll
    for (int j = 0; j < 16; j++) {
        if (j < nv) sl[j] = atomicAdd(&cnt[D[j] >> BSH], 1);
    }
    __syncthreads();
    for (int i = tid; i < nbins; i += 256) {
        int cv = cnt[i];
        base[i] = cv ? atomicAdd(&cursor[i * CSTRIDE], cv) : 0;
    }
    __syncthreads();
#pragma unroll
    for (int j = 0; j < 16; j++) {
        if (j < nv) {
            int b = D[j] >> BSH;
            int pos = base[b] + sl[j];
            if (pos < maxBin)
                staging[(size_t)b * maxBin + pos] =
                    (unsigned)S[j] | ((unsigned)(D[j] & (BINW - 1)) << 16);
        }
    }
}

// ---------------------------------------------------------------------------
// K2: fused [bin deg-hist -> dinv] + [g(bf16) = dinv*(x @ W) via MFMA].
// R7-proven verbatim: deg from segment scan (no global atomics — R21),
// 391 blocks x 512 thr, W B-fragment-major LDS, cvt_pk pack.
// ---------------------------------------------------------------------------
__global__ __launch_bounds__(512, 4) void gemm_mfma(const float* __restrict__ x,
                                                    const float* __restrict__ W,
                                                    const unsigned* __restrict__ staging,
                                                    const int* __restrict__ cursor,
                                                    unsigned* __restrict__ gu,
                                                    int N, int maxBin) {
    __shared__ unsigned Wf[32 * 64 * 4];  // 32 KB: [kchunk][n][4 x u32(bf16x2)]
    __shared__ int degL[BINW];
    __shared__ float dinvL[BINW];
    const int b = blockIdx.x;
    const int tid = threadIdx.x;

    if (tid < BINW) degL[tid] = 0;
    for (int p = tid; p < (F_IN / 2) * F_OUT; p += 512) {
        int kp = p >> 6;
        int n = p & 63;
        int k = kp * 2;
        Wf[((k >> 3) * 64 + n) * 4 + ((k & 7) >> 1)] =
            cvt_pk_bf16(W[k * F_OUT + n], W[(k + 1) * F_OUT + n]);
    }
    __syncthreads();

    const int segCnt = min(cursor[b * CSTRIDE], maxBin);
    const unsigned* seg = staging + (size_t)b * maxBin;
    for (int i = tid; i < segCnt; i += 512) atomicAdd(&degL[seg[i] >> 16], 1);
    __syncthreads();
    if (tid < BINW) dinvL[tid] = rsqrtf((float)degL[tid] + 1.0f);
    __syncthreads();

    const int wave = tid >> 6;
    const int lane = tid & 63;
    const int q = lane >> 4;
    const int c = lane & 15;
    const int n0 = b * 128 + wave * 16;
    const int r = min(n0 + c, N - 1);
    const float* p0 = x + (size_t)r * F_IN + q * 8;

    f32x4 acc[4] = {};
#pragma unroll
    for (int s = 0; s < 8; s++) {
        float4 a0 = *(const float4*)(p0 + s * 32);
        float4 a1 = *(const float4*)(p0 + s * 32 + 4);
        short8 ah = pack_cvt(a0, a1);
#pragma unroll
        for (int t = 0; t < 4; t++) {
            short8 bh = *(const short8*)&Wf[((s * 4 + q) * 64 + t * 16 + c) * 4];
            acc[t] = __builtin_amdgcn_mfma_f32_16x16x32_bf16(ah, bh, acc[t], 0, 0, 0);
        }
    }

    // D layout: col = t*16 + c (feature), row = q*4 + rr (node). Pack col
    // pairs via shfl_xor(1), store bf16x2.
#pragma unroll
    for (int rr = 0; rr < 4; rr++) {
        int node = n0 + q * 4 + rr;
        float dv = dinvL[wave * 16 + q * 4 + rr];
#pragma unroll
        for (int t = 0; t < 4; t++) {
            float v = acc[t][rr] * dv;
            float o = __shfl_xor(v, 1, 64);
            if (node < N && !(lane & 1)) {
                gu[(size_t)node * 32 + t * 8 + (c >> 1)] = cvt_pk_bf16(v, o);
            }
        }
    }
}

// ---------------------------------------------------------------------------
// K3: gather via bin-local CSR in LDS. R23 change (single variable vs R12):
// one node PER 8-LANE GROUP (node = wv*8+grp) instead of 8 groups on one
// node serially — all 8 nodes per wave proceed in parallel, the 3-level
// shfl_xor cross-group reduce disappears (each lane owns its h-chunk
// end-to-end), 4-deep edge unroll gives 32 gathered rows in flight/wave
// (was 16), and the epilogue store is one contiguous 2KB/wave. CSR-build
// prologue verbatim R12 (1024 thr, 3 rounds).
// ---------------------------------------------------------------------------
__global__ __launch_bounds__(1024) void gather_bin(const unsigned* __restrict__ staging,
                                                   const int* __restrict__ cursor,
                                                   const unsigned* __restrict__ g32,
                                                   const float* __restrict__ bias,
                                                   float* __restrict__ out,
                                                   int N, int maxBin) {
    __shared__ int cnt[BINW];
    __shared__ int off[BINW];
    __shared__ int wsum[2];
    __shared__ unsigned short binCsr[MAXBIN_CAP];
    const int b = blockIdx.x;
    const int tid = threadIdx.x;
    const int nb0 = b << BSH;

    if (tid < BINW) cnt[tid] = 0;
    __syncthreads();

    const int segCnt = min(cursor[b * CSTRIDE], maxBin);
    const unsigned* seg = staging + (size_t)b * maxBin;

    unsigned ev[3];
    int sl[3];
    int nv = 0;
#pragma unroll
    for (int r = 0; r < 3; r++) {
        int i = tid + r * 1024;
        if (i < segCnt) {
            unsigned e = seg[i];
            ev[r] = e;
            sl[r] = atomicAdd(&cnt[e >> 16], 1);
            nv = r + 1;
        }
    }
    __syncthreads();

    int incl = 0, v = 0;
    if (tid < BINW) {  // 2-wave exclusive scan of cnt[128]
        v = cnt[tid];
        incl = v;
        const int lane = tid & 63;
        for (int d = 1; d < 64; d <<= 1) {
            int t = __shfl_up(incl, d, 64);
            if (lane >= d) incl += t;
        }
        if (lane == 63) wsum[tid >> 6] = incl;
    }
    __syncthreads();
    if (tid < BINW) off[tid] = incl - v + ((tid >= 64) ? wsum[0] : 0);
    __syncthreads();

#pragma unroll
    for (int r = 0; r < 3; r++) {
        if (r < nv) binCsr[off[ev[r] >> 16] + sl[r]] = (unsigned short)(ev[r] & 0xFFFFu);
    }
    __syncthreads();

    const int wv = tid >> 6;     // 0..15
    const int lane = tid & 63;
    const int grp = lane >> 3;   // 0..7: this group's node
    const int h = lane & 7;      // feature chunk (8 floats)
    const int node = wv * 8 + grp;
    const int gn = nb0 + node;
    const uint4* g4 = (const uint4*)g32;

    if (gn < N) {
        const int start = off[node];
        const int deg = cnt[node];

        float a0[8] = {}, a1[8] = {};
        int i = 0;
        for (; i + 4 <= deg; i += 4) {  // 4 rows in flight per group
            int s0 = binCsr[start + i], s1 = binCsr[start + i + 1];
            int s2 = binCsr[start + i + 2], s3 = binCsr[start + i + 3];
            uint4 u0 = g4[(size_t)s0 * 8 + h];
            uint4 u1 = g4[(size_t)s1 * 8 + h];
            uint4 u2 = g4[(size_t)s2 * 8 + h];
            uint4 u3 = g4[(size_t)s3 * 8 + h];
            a0[0] += bf_lo(u0.x); a0[1] += bf_hi(u0.x);
            a0[2] += bf_lo(u0.y); a0[3] += bf_hi(u0.y);
            a0[4] += bf_lo(u0.z); a0[5] += bf_hi(u0.z);
            a0[6] += bf_lo(u0.w); a0[7] += bf_hi(u0.w);
            a1[0] += bf_lo(u1.x); a1[1] += bf_hi(u1.x);
            a1[2] += bf_lo(u1.y); a1[3] += bf_hi(u1.y);
            a1[4] += bf_lo(u1.z); a1[5] += bf_hi(u1.z);
            a1[6] += bf_lo(u1.w); a1[7] += bf_hi(u1.w);
            a0[0] += bf_lo(u2.x); a0[1] += bf_hi(u2.x);
            a0[2] += bf_lo(u2.y); a0[3] += bf_hi(u2.y);
            a0[4] += bf_lo(u2.z); a0[5] += bf_hi(u2.z);
            a0[6] += bf_lo(u2.w); a0[7] += bf_hi(u2.w);
            a1[0] += bf_lo(u3.x); a1[1] += bf_hi(u3.x);
            a1[2] += bf_lo(u3.y); a1[3] += bf_hi(u3.y);
            a1[4] += bf_lo(u3.z); a1[5] += bf_hi(u3.z);
            a1[6] += bf_lo(u3.w); a1[7] += bf_hi(u3.w);
        }
        for (; i < deg; i++) {
            int s0 = binCsr[start + i];
            uint4 u0 = g4[(size_t)s0 * 8 + h];
            a0[0] += bf_lo(u0.x); a0[1] += bf_hi(u0.x);
            a0[2] += bf_lo(u0.y); a0[3] += bf_hi(u0.y);
            a0[4] += bf_lo(u0.z); a0[5] += bf_hi(u0.z);
            a0[6] += bf_lo(u0.w); a0[7] += bf_hi(u0.w);
        }

        uint4 us = g4[(size_t)gn * 8 + h];  // self loop (dinv-prescaled)
        float dv = rsqrtf((float)deg + 1.0f);
        float s0 = bf_lo(us.x), s1 = bf_hi(us.x), s2 = bf_lo(us.y), s3 = bf_hi(us.y);
        float s4 = bf_lo(us.z), s5 = bf_hi(us.z), s6 = bf_lo(us.w), s7 = bf_hi(us.w);
        float4 b0 = *(const float4*)&bias[h * 8];
        float4 b1 = *(const float4*)&bias[h * 8 + 4];
        float4 r0, r1;
        r0.x = fmaxf(fmaf(dv, a0[0] + a1[0] + s0, b0.x), 0.0f);
        r0.y = fmaxf(fmaf(dv, a0[1] + a1[1] + s1, b0.y), 0.0f);
        r0.z = fmaxf(fmaf(dv, a0[2] + a1[2] + s2, b0.z), 0.0f);
        r0.w = fmaxf(fmaf(dv, a0[3] + a1[3] + s3, b0.w), 0.0f);
        r1.x = fmaxf(fmaf(dv, a0[4] + a1[4] + s4, b1.x), 0.0f);
        r1.y = fmaxf(fmaf(dv, a0[5] + a1[5] + s5, b1.y), 0.0f);
        r1.z = fmaxf(fmaf(dv, a0[6] + a1[6] + s6, b1.z), 0.0f);
        r1.w = fmaxf(fmaf(dv, a0[7] + a1[7] + s7, b1.w), 0.0f);
        *(float4*)&out[(size_t)gn * F_OUT + h * 8] = r0;
        *(float4*)&out[(size_t)gn * F_OUT + h * 8 + 4] = r1;
    }
}

extern "C" void kernel_launch(void* const* d_in, const int* in_sizes, int n_in,
                              void* d_out, int out_size, void* d_ws, size_t ws_size,
                              hipStream_t stream) {
    const float* x = (const float*)d_in[0];
    const int* adj = (const int*)d_in[1];
    const float* W = (const float*)d_in[2];
    const float* b = (const float*)d_in[3];
    float* out = (float*)d_out;

    const int N = in_sizes[0] / F_IN;  // 50000 (u16 packing assumes N <= 65536)
    const int E = in_sizes[1] / 2;     // 800000
    const int nbins = (N + BINW - 1) >> BSH;  // 391 (<= NBINS_CAP)
    const int maxBin = MAXBIN_CAP;            // 2560, ~11 sd above mean 2047

    // ws: cursor(nbins*64B, zeroed) | staging(nbins*maxBin u32) | g16(N*32 u32)
    char* ws = (char*)d_ws;
    size_t segCur = (((size_t)nbins * CSTRIDE * 4) + 255) & ~(size_t)255;
    size_t segStg = (((size_t)nbins * maxBin * 4) + 255) & ~(size_t)255;
    int* cursor = (int*)ws;
    unsigned* staging = (unsigned*)(ws + segCur);
    unsigned* g16 = (unsigned*)(ws + segCur + segStg);

    hipMemsetAsync(cursor, 0, segCur, stream);

    bin_count<<<(E + BATCH - 1) / BATCH, 256, 0, stream>>>(adj, staging, cursor,
                                                           E, nbins, maxBin);
    gemm_mfma<<<nbins, 512, 0, stream>>>(x, W, staging, cursor, g16, N, maxBin);
    gather_bin<<<nbins, 1024, 0, stream>>>(staging, cursor, g16, b, out, N, maxBin);
}